// Round 1
// baseline (132.099 us; speedup 1.0000x reference)
//
#include <hip/hip_runtime.h>

// Problem constants
#define BATCH 64
#define GH 14
#define GW 14
#define NPATCH (GH*GW)        // 196
#define M_ROWS (BATCH*NPATCH) // 12544
#define KDIM 768              // 3*16*16
#define DDIM 384              // EMBED
#define HW (224*224)

typedef __attribute__((ext_vector_type(8))) short s16x8;
typedef __attribute__((ext_vector_type(4))) float f32x4;
typedef __attribute__((ext_vector_type(4))) unsigned short u16x4;

__device__ __forceinline__ unsigned short f2bf(float f) {
    unsigned int u = __float_as_uint(f);
    u += 0x7fff + ((u >> 16) & 1);   // round-to-nearest-even
    return (unsigned short)(u >> 16);
}

__device__ __forceinline__ void load_lds16(const void* g, void* l) {
    __builtin_amdgcn_global_load_lds(
        (const __attribute__((address_space(1))) unsigned int*)g,
        (__attribute__((address_space(3))) unsigned int*)l, 16, 0, 0);
}

// ---------------- kernel 1: weights fp32 -> bf16 (384x768 row-major, = B^T) --
__global__ __launch_bounds__(256) void wcast_kernel(const float* __restrict__ w,
                                                    unsigned short* __restrict__ W) {
    int t = blockIdx.x * 256 + threadIdx.x;   // 73728 float4s
    float4 v = ((const float4*)w)[t];
    u16x4 o = { f2bf(v.x), f2bf(v.y), f2bf(v.z), f2bf(v.w) };
    *(u16x4*)(W + t * 4) = o;
}

// ---------------- kernel 2: im2col + bf16 cast -------------------------------
// A[row][k], row = b*196 + ph*14 + pw, k = c*256 + r*16 + col
__global__ __launch_bounds__(256) void im2col_kernel(const float* __restrict__ img,
                                                     unsigned short* __restrict__ A) {
    int t = blockIdx.x * 256 + threadIdx.x;   // 2408448 float4s
    float4 v = ((const float4*)img)[t];
    int x4   = t % 56;
    int rest = t / 56;
    int y    = rest % 224;
    int bc   = rest / 224;          // b*3 + c
    int b = bc / 3, c = bc - 3 * b;
    int ph = y >> 4, r = y & 15;
    int pw = x4 >> 2, col = (x4 & 3) * 4;
    int row = b * NPATCH + ph * GW + pw;
    int k   = c * 256 + r * 16 + col;
    u16x4 o = { f2bf(v.x), f2bf(v.y), f2bf(v.z), f2bf(v.w) };
    *(u16x4*)(A + row * KDIM + k) = o;
}

// ---------------- kernel 3: patch entropy ------------------------------------
__global__ __launch_bounds__(256) void entropy_kernel(const float* __restrict__ img,
                                                      float* __restrict__ ent) {
    __shared__ int hist[4][32];
    const int lane = threadIdx.x & 63;
    const int wave = threadIdx.x >> 6;
    const int p = blockIdx.x * 4 + wave;      // 0..12543
    const int b = p / NPATCH;
    const int n = p - b * NPATCH;
    const int ph = n / GW, pw = n - ph * GW;

    if (lane < 32) hist[wave][lane] = 0;
    __syncthreads();

    const float* base = img + b * (3 * HW) + (ph * 16) * 224 + pw * 16;
#pragma unroll
    for (int j = 0; j < 4; ++j) {
        int idx = lane + 64 * j;              // 0..255
        int r = idx >> 4, cc = idx & 15;
        const float* px = base + r * 224 + cc;
        float g = (px[0] + px[HW] + px[2 * HW]) / 3.0f;
        int bin = (int)(g * 31.0f);
        bin = bin < 0 ? 0 : (bin > 31 ? 31 : bin);
        atomicAdd(&hist[wave][bin], 1);
    }
    __syncthreads();

    float t = 0.0f;
    if (lane < 32) {
        float pr = (float)hist[wave][lane] * (1.0f / 256.0f);
        t = -pr * log2f(pr + 1e-10f);
    }
#pragma unroll
    for (int off = 32; off; off >>= 1) t += __shfl_xor(t, off);
    if (lane == 0) ent[p] = t * (1.0f / 5.0f);   // / log2(32)
}

// ---------------- kernel 4: bf16 MFMA GEMM, C = A * Bt^T + bias --------------
// A: (12544 x 768) bf16 row-major. Bt: (384 x 768) bf16 row-major (N x K).
// 128x128 tile, BK=64, 256 threads = 4 waves in 2x2, each wave 64x64.
__global__ __launch_bounds__(256) void gemm_kernel(const unsigned short* __restrict__ A,
                                                   const unsigned short* __restrict__ Bt,
                                                   const float* __restrict__ bias,
                                                   float* __restrict__ C) {
    __shared__ __align__(16) unsigned short As[128 * 64];
    __shared__ __align__(16) unsigned short Bs[128 * 64];
    const int tid  = threadIdx.x;
    const int lane = tid & 63;
    const int wave = tid >> 6;
    const int wm = wave >> 1, wn = wave & 1;
    const int rowBase = blockIdx.y * 128;
    const int colBase = blockIdx.x * 128;

    f32x4 acc[4][4] = {};

    for (int kt = 0; kt < KDIM; kt += 64) {
        // stage 128x64 of A and of Bt: 4 issues x 256 lanes x 16B each
#pragma unroll
        for (int i = 0; i < 4; ++i) {
            int f = i * 256 + tid;            // 0..1023
            int r = f >> 3, ks = f & 7;
            load_lds16(A  + (rowBase + r) * KDIM + kt + ks * 8, (unsigned short*)As + f * 8);
            load_lds16(Bt + (colBase + r) * KDIM + kt + ks * 8, (unsigned short*)Bs + f * 8);
        }
        __syncthreads();
#pragma unroll
        for (int ks = 0; ks < 2; ++ks) {
            const int ko = ks * 32 + (lane >> 4) * 8;
            s16x8 a_frag[4], b_frag[4];
#pragma unroll
            for (int i = 0; i < 4; ++i) {
                int m = wm * 64 + i * 16 + (lane & 15);
                a_frag[i] = *(const s16x8*)(As + m * 64 + ko);
                int n = wn * 64 + i * 16 + (lane & 15);
                b_frag[i] = *(const s16x8*)(Bs + n * 64 + ko);
            }
#pragma unroll
            for (int i = 0; i < 4; ++i)
#pragma unroll
                for (int j = 0; j < 4; ++j)
                    acc[i][j] = __builtin_amdgcn_mfma_f32_16x16x32_bf16(
                        a_frag[i], b_frag[j], acc[i][j], 0, 0, 0);
        }
        __syncthreads();
    }

    // epilogue: C/D layout col = lane&15, row = (lane>>4)*4 + reg
    const int quad = lane >> 4;
    const int cl = lane & 15;
#pragma unroll
    for (int j = 0; j < 4; ++j) {
        int col = colBase + wn * 64 + j * 16 + cl;
        float bv = bias[col];
#pragma unroll
        for (int i = 0; i < 4; ++i) {
            int row0 = rowBase + wm * 64 + i * 16 + quad * 4;
#pragma unroll
            for (int r = 0; r < 4; ++r)
                C[(size_t)(row0 + r) * DDIM + col] = acc[i][j][r] + bv;
        }
    }
}

// ---------------- kernel 5: LayerNorm (in-place on d_out x-region) -----------
__global__ __launch_bounds__(256) void ln_kernel(float* __restrict__ X,
                                                 const float* __restrict__ gamma,
                                                 const float* __restrict__ beta) {
    __shared__ float sg[DDIM], sb[DDIM];
    for (int i = threadIdx.x; i < DDIM; i += 256) { sg[i] = gamma[i]; sb[i] = beta[i]; }
    __syncthreads();
    const int lane = threadIdx.x & 63;
    const int wave = threadIdx.x >> 6;
    const int row = blockIdx.x * 4 + wave;
    float* x = X + (size_t)row * DDIM + lane * 6;

    float2 p0 = *(float2*)(x);
    float2 p1 = *(float2*)(x + 2);
    float2 p2 = *(float2*)(x + 4);
    float v[6] = { p0.x, p0.y, p1.x, p1.y, p2.x, p2.y };

    float s = v[0] + v[1] + v[2] + v[3] + v[4] + v[5];
#pragma unroll
    for (int off = 32; off; off >>= 1) s += __shfl_xor(s, off);
    float mean = s * (1.0f / (float)DDIM);

    float d = 0.0f;
#pragma unroll
    for (int j = 0; j < 6; ++j) { float t = v[j] - mean; d += t * t; }
#pragma unroll
    for (int off = 32; off; off >>= 1) d += __shfl_xor(d, off);
    float rstd = 1.0f / sqrtf(d * (1.0f / (float)DDIM) + 1e-5f);

    const float* g = sg + lane * 6;
    const float* b = sb + lane * 6;
#pragma unroll
    for (int j = 0; j < 6; ++j) x[j] = (v[j] - mean) * rstd * g[j] + b[j];
}

extern "C" void kernel_launch(void* const* d_in, const int* in_sizes, int n_in,
                              void* d_out, int out_size, void* d_ws, size_t ws_size,
                              hipStream_t stream) {
    const float* img = (const float*)d_in[0];
    const float* pw  = (const float*)d_in[1];
    const float* pb  = (const float*)d_in[2];
    const float* gam = (const float*)d_in[3];
    const float* bet = (const float*)d_in[4];
    float* out = (float*)d_out;

    unsigned short* Abf = (unsigned short*)d_ws;                       // 12544*768*2 = 19267584 B
    unsigned short* Wbf = (unsigned short*)((char*)d_ws + 19267584);   // 384*768*2  = 589824 B
    float* ent = out + (size_t)M_ROWS * DDIM;                          // entropy after x

    hipLaunchKernelGGL(wcast_kernel,   dim3(288),    dim3(256), 0, stream, pw, Wbf);
    hipLaunchKernelGGL(im2col_kernel,  dim3(9408),   dim3(256), 0, stream, img, Abf);
    hipLaunchKernelGGL(entropy_kernel, dim3(3136),   dim3(256), 0, stream, img, ent);
    hipLaunchKernelGGL(gemm_kernel,    dim3(3, 98),  dim3(256), 0, stream, Abf, Wbf, pb, out);
    hipLaunchKernelGGL(ln_kernel,      dim3(3136),   dim3(256), 0, stream, out, gam, bet);
}

// Round 2
// 123.432 us; speedup vs baseline: 1.0702x; 1.0702x over previous
//
#include <hip/hip_runtime.h>

// Problem constants
#define BATCH 64
#define GH 14
#define GW 14
#define NPATCH (GH*GW)        // 196
#define M_ROWS (BATCH*NPATCH) // 12544
#define KDIM 768              // 3*16*16
#define DDIM 384              // EMBED
#define HW (224*224)

typedef __attribute__((ext_vector_type(8))) short s16x8;
typedef __attribute__((ext_vector_type(4))) float f32x4;
typedef __attribute__((ext_vector_type(4))) unsigned short u16x4;

__device__ __forceinline__ unsigned short f2bf(float f) {
    unsigned int u = __float_as_uint(f);
    u += 0x7fff + ((u >> 16) & 1);   // round-to-nearest-even
    return (unsigned short)(u >> 16);
}

__device__ __forceinline__ void load_lds16(const void* g, void* l) {
    __builtin_amdgcn_global_load_lds(
        (const __attribute__((address_space(1))) unsigned int*)g,
        (__attribute__((address_space(3))) unsigned int*)l, 16, 0, 0);
}

// ---------------- kernel 1: weights fp32 -> bf16 (384x768 row-major = B^T) ---
__global__ __launch_bounds__(256) void wcast_kernel(const float* __restrict__ w,
                                                    unsigned short* __restrict__ W) {
    int t = blockIdx.x * 256 + threadIdx.x;   // 73728 float4s
    float4 v = ((const float4*)w)[t];
    u16x4 o = { f2bf(v.x), f2bf(v.y), f2bf(v.z), f2bf(v.w) };
    *(u16x4*)(W + t * 4) = o;
}

// ---------------- kernel 2: fused im2col(bf16) + patch entropy ---------------
// One wave per patch. Lane l loads float4 #l of each channel (4 px in a row),
// writes bf16 to A[row][c*256 + l*4], and histograms the grayscale.
__global__ __launch_bounds__(256) void patch_kernel(const float* __restrict__ img,
                                                    unsigned short* __restrict__ A,
                                                    float* __restrict__ ent) {
    __shared__ int hist[4][32];
    const int lane = threadIdx.x & 63;
    const int wave = threadIdx.x >> 6;
    const int p = blockIdx.x * 4 + wave;      // 0..12543 == A row index
    const int b = p / NPATCH;
    const int n = p - b * NPATCH;
    const int ph = n / GW, pw = n - ph * GW;

    if (lane < 32) hist[wave][lane] = 0;
    __syncthreads();

    const int r = lane >> 2;                  // pixel row in patch 0..15
    const int cc = (lane & 3) * 4;            // pixel col 0,4,8,12
    const float* base = img + (size_t)b * (3 * HW) + (ph * 16 + r) * 224 + pw * 16 + cc;

    float4 v0 = *(const float4*)(base);
    float4 v1 = *(const float4*)(base + HW);
    float4 v2 = *(const float4*)(base + 2 * HW);

    unsigned short* arow = A + (size_t)p * KDIM;
    u16x4 o0 = { f2bf(v0.x), f2bf(v0.y), f2bf(v0.z), f2bf(v0.w) };
    u16x4 o1 = { f2bf(v1.x), f2bf(v1.y), f2bf(v1.z), f2bf(v1.w) };
    u16x4 o2 = { f2bf(v2.x), f2bf(v2.y), f2bf(v2.z), f2bf(v2.w) };
    *(u16x4*)(arow + 0 * 256 + lane * 4) = o0;
    *(u16x4*)(arow + 1 * 256 + lane * 4) = o1;
    *(u16x4*)(arow + 2 * 256 + lane * 4) = o2;

    float g[4] = { (v0.x + v1.x + v2.x) / 3.0f,
                   (v0.y + v1.y + v2.y) / 3.0f,
                   (v0.z + v1.z + v2.z) / 3.0f,
                   (v0.w + v1.w + v2.w) / 3.0f };
#pragma unroll
    for (int j = 0; j < 4; ++j) {
        int bin = (int)(g[j] * 31.0f);
        bin = bin < 0 ? 0 : (bin > 31 ? 31 : bin);
        atomicAdd(&hist[wave][bin], 1);
    }
    __syncthreads();

    float t = 0.0f;
    if (lane < 32) {
        float pr = (float)hist[wave][lane] * (1.0f / 256.0f);
        t = -pr * log2f(pr + 1e-10f);
    }
#pragma unroll
    for (int off = 32; off; off >>= 1) t += __shfl_xor(t, off);
    if (lane == 0) ent[p] = t * (1.0f / 5.0f);   // / log2(32)
}

// ---------------- kernel 3: bf16 MFMA GEMM, C = A * Bt^T + bias --------------
// One wave per block, 64x64 tile (m97's per-wave config: 4x4 acc, BK=64).
// Grid (6, 196) = 1176 blocks -> ~4.6 blocks/CU for load balance/overlap.
__global__ __launch_bounds__(64) void gemm_kernel(const unsigned short* __restrict__ A,
                                                  const unsigned short* __restrict__ Bt,
                                                  const float* __restrict__ bias,
                                                  float* __restrict__ C) {
    __shared__ __align__(16) unsigned short As[64 * 64];
    __shared__ __align__(16) unsigned short Bs[64 * 64];
    const int lane = threadIdx.x;
    const int rowBase = blockIdx.y * 64;
    const int colBase = blockIdx.x * 64;

    f32x4 acc[4][4] = {};

    for (int kt = 0; kt < KDIM; kt += 64) {
        // stage 64x64 of A and Bt: 512 16B-chunks each, 64 lanes x 8 issues
#pragma unroll
        for (int i = 0; i < 8; ++i) {
            int f = i * 64 + lane;            // 0..511
            int r = f >> 3, ks = f & 7;
            load_lds16(A  + (size_t)(rowBase + r) * KDIM + kt + ks * 8, (unsigned short*)As + f * 8);
            load_lds16(Bt + (size_t)(colBase + r) * KDIM + kt + ks * 8, (unsigned short*)Bs + f * 8);
        }
        __syncthreads();
#pragma unroll
        for (int ks = 0; ks < 2; ++ks) {
            const int ko = ks * 32 + (lane >> 4) * 8;
            s16x8 a_frag[4], b_frag[4];
#pragma unroll
            for (int i = 0; i < 4; ++i) {
                a_frag[i] = *(const s16x8*)(As + (i * 16 + (lane & 15)) * 64 + ko);
                b_frag[i] = *(const s16x8*)(Bs + (i * 16 + (lane & 15)) * 64 + ko);
            }
#pragma unroll
            for (int i = 0; i < 4; ++i)
#pragma unroll
                for (int j = 0; j < 4; ++j)
                    acc[i][j] = __builtin_amdgcn_mfma_f32_16x16x32_bf16(
                        a_frag[i], b_frag[j], acc[i][j], 0, 0, 0);
        }
        __syncthreads();
    }

    // epilogue: C/D layout col = lane&15, row = (lane>>4)*4 + reg
    const int quad = lane >> 4;
    const int cl = lane & 15;
#pragma unroll
    for (int j = 0; j < 4; ++j) {
        int col = colBase + j * 16 + cl;
        float bv = bias[col];
#pragma unroll
        for (int i = 0; i < 4; ++i) {
            int row0 = rowBase + i * 16 + quad * 4;
#pragma unroll
            for (int r = 0; r < 4; ++r)
                C[(size_t)(row0 + r) * DDIM + col] = acc[i][j][r] + bv;
        }
    }
}

// ---------------- kernel 4: LayerNorm (in-place on d_out x-region) -----------
__global__ __launch_bounds__(256) void ln_kernel(float* __restrict__ X,
                                                 const float* __restrict__ gamma,
                                                 const float* __restrict__ beta) {
    __shared__ float sg[DDIM], sb[DDIM];
    for (int i = threadIdx.x; i < DDIM; i += 256) { sg[i] = gamma[i]; sb[i] = beta[i]; }
    __syncthreads();
    const int lane = threadIdx.x & 63;
    const int wave = threadIdx.x >> 6;
    const int row = blockIdx.x * 4 + wave;
    float* x = X + (size_t)row * DDIM + lane * 6;

    float2 p0 = *(float2*)(x);
    float2 p1 = *(float2*)(x + 2);
    float2 p2 = *(float2*)(x + 4);
    float v[6] = { p0.x, p0.y, p1.x, p1.y, p2.x, p2.y };

    float s = v[0] + v[1] + v[2] + v[3] + v[4] + v[5];
#pragma unroll
    for (int off = 32; off; off >>= 1) s += __shfl_xor(s, off);
    float mean = s * (1.0f / (float)DDIM);

    float d = 0.0f;
#pragma unroll
    for (int j = 0; j < 6; ++j) { float t = v[j] - mean; d += t * t; }
#pragma unroll
    for (int off = 32; off; off >>= 1) d += __shfl_xor(d, off);
    float rstd = 1.0f / sqrtf(d * (1.0f / (float)DDIM) + 1e-5f);

    const float* g = sg + lane * 6;
    const float* b = sb + lane * 6;
#pragma unroll
    for (int j = 0; j < 6; ++j) x[j] = (v[j] - mean) * rstd * g[j] + b[j];
}

extern "C" void kernel_launch(void* const* d_in, const int* in_sizes, int n_in,
                              void* d_out, int out_size, void* d_ws, size_t ws_size,
                              hipStream_t stream) {
    const float* img = (const float*)d_in[0];
    const float* pw  = (const float*)d_in[1];
    const float* pb  = (const float*)d_in[2];
    const float* gam = (const float*)d_in[3];
    const float* bet = (const float*)d_in[4];
    float* out = (float*)d_out;

    unsigned short* Abf = (unsigned short*)d_ws;                       // 12544*768*2 = 19267584 B
    unsigned short* Wbf = (unsigned short*)((char*)d_ws + 19267584);   // 384*768*2  = 589824 B
    float* ent = out + (size_t)M_ROWS * DDIM;                          // entropy after x

    hipLaunchKernelGGL(wcast_kernel, dim3(288),      dim3(256), 0, stream, pw, Wbf);
    hipLaunchKernelGGL(patch_kernel, dim3(3136),     dim3(256), 0, stream, img, Abf, ent);
    hipLaunchKernelGGL(gemm_kernel,  dim3(6, 196),   dim3(64),  0, stream, Abf, Wbf, pb, out);
    hipLaunchKernelGGL(ln_kernel,    dim3(3136),     dim3(256), 0, stream, out, gam, bet);
}

// Round 3
// 114.422 us; speedup vs baseline: 1.1545x; 1.0787x over previous
//
#include <hip/hip_runtime.h>

// Problem constants
#define BATCH 64
#define GH 14
#define GW 14
#define NPATCH (GH*GW)        // 196
#define M_ROWS (BATCH*NPATCH) // 12544
#define KDIM 768              // 3*16*16
#define DDIM 384              // EMBED
#define HW (224*224)

typedef __attribute__((ext_vector_type(8))) short s16x8;
typedef __attribute__((ext_vector_type(4))) float f32x4;
typedef __attribute__((ext_vector_type(4))) unsigned short u16x4;

__device__ __forceinline__ unsigned short f2bf(float f) {
    unsigned int u = __float_as_uint(f);
    u += 0x7fff + ((u >> 16) & 1);   // round-to-nearest-even
    return (unsigned short)(u >> 16);
}

__device__ __forceinline__ void load_lds16(const void* g, void* l) {
    __builtin_amdgcn_global_load_lds(
        (const __attribute__((address_space(1))) unsigned int*)g,
        (__attribute__((address_space(3))) unsigned int*)l, 16, 0, 0);
}

// ------- kernel 1: fused im2col(bf16) + patch entropy + weight cast ----------
// blocks [0,3136): one wave per patch -> bf16 A row + grayscale histogram.
// blocks [3136,3424): weight fp32->bf16 cast (384x768 row-major = B^T).
__global__ __launch_bounds__(256) void patch_kernel(const float* __restrict__ img,
                                                    const float* __restrict__ w,
                                                    unsigned short* __restrict__ A,
                                                    unsigned short* __restrict__ W,
                                                    float* __restrict__ ent) {
    if (blockIdx.x >= 3136) {                 // ---- weight cast part ----
        int t = (blockIdx.x - 3136) * 256 + threadIdx.x;   // 73728 float4s
        float4 v = ((const float4*)w)[t];
        u16x4 o = { f2bf(v.x), f2bf(v.y), f2bf(v.z), f2bf(v.w) };
        *(u16x4*)(W + t * 4) = o;
        return;
    }
    __shared__ int hist[4][32];
    const int lane = threadIdx.x & 63;
    const int wave = threadIdx.x >> 6;
    const int p = blockIdx.x * 4 + wave;      // 0..12543 == A row index
    const int b = p / NPATCH;
    const int n = p - b * NPATCH;
    const int ph = n / GW, pw = n - ph * GW;

    if (lane < 32) hist[wave][lane] = 0;
    __syncthreads();

    const int r = lane >> 2;                  // pixel row in patch 0..15
    const int cc = (lane & 3) * 4;            // pixel col 0,4,8,12
    const float* base = img + (size_t)b * (3 * HW) + (ph * 16 + r) * 224 + pw * 16 + cc;

    float4 v0 = *(const float4*)(base);
    float4 v1 = *(const float4*)(base + HW);
    float4 v2 = *(const float4*)(base + 2 * HW);

    unsigned short* arow = A + (size_t)p * KDIM;
    u16x4 o0 = { f2bf(v0.x), f2bf(v0.y), f2bf(v0.z), f2bf(v0.w) };
    u16x4 o1 = { f2bf(v1.x), f2bf(v1.y), f2bf(v1.z), f2bf(v1.w) };
    u16x4 o2 = { f2bf(v2.x), f2bf(v2.y), f2bf(v2.z), f2bf(v2.w) };
    *(u16x4*)(arow + 0 * 256 + lane * 4) = o0;
    *(u16x4*)(arow + 1 * 256 + lane * 4) = o1;
    *(u16x4*)(arow + 2 * 256 + lane * 4) = o2;

    float g[4] = { (v0.x + v1.x + v2.x) / 3.0f,
                   (v0.y + v1.y + v2.y) / 3.0f,
                   (v0.z + v1.z + v2.z) / 3.0f,
                   (v0.w + v1.w + v2.w) / 3.0f };
#pragma unroll
    for (int j = 0; j < 4; ++j) {
        int bin = (int)(g[j] * 31.0f);
        bin = bin < 0 ? 0 : (bin > 31 ? 31 : bin);
        atomicAdd(&hist[wave][bin], 1);
    }
    __syncthreads();

    float t = 0.0f;
    if (lane < 32) {
        float pr = (float)hist[wave][lane] * (1.0f / 256.0f);
        t = -pr * log2f(pr + 1e-10f);
    }
#pragma unroll
    for (int off = 32; off; off >>= 1) t += __shfl_xor(t, off);
    if (lane == 0) ent[p] = t * (1.0f / 5.0f);   // / log2(32)
}

// ------- kernel 2: bf16 MFMA GEMM (64 rows x full 384 cols) + bias + LN ------
// 384 threads = 6 waves; wave w does cols [w*64, w*64+64). BK=64, 12 K-iters.
// XOR-swizzled LDS: slot ks holds global chunk ks^(row&7) -> uniform
// 8-lanes-per-bank-group on every ds_read_b128 (theoretical LDS minimum).
// Epilogue: per-row mean/var via shuffle + LDS atomics, write normalized out.
__global__ __launch_bounds__(384) void gemm_ln_kernel(const unsigned short* __restrict__ A,
                                                      const unsigned short* __restrict__ Bt,
                                                      const float* __restrict__ bias,
                                                      const float* __restrict__ gamma,
                                                      const float* __restrict__ beta,
                                                      float* __restrict__ C) {
    __shared__ __align__(16) unsigned short SH[(64 + 384) * 64];  // As | Bs, 56 KB
    __shared__ float sred[64], sred2[64], smean[64], srstd[64];
    unsigned short* As = SH;
    unsigned short* Bs = SH + 64 * 64;

    const int tid  = threadIdx.x;
    const int lane = tid & 63;
    const int w    = tid >> 6;                // wave 0..5
    const int quad = lane >> 4;
    const int cl   = lane & 15;
    const int rowBase = blockIdx.x * 64;

    if (tid < 64) { sred[tid] = 0.0f; sred2[tid] = 0.0f; }

    f32x4 acc[4][4] = {};

    for (int kt = 0; kt < KDIM; kt += 64) {
        // stage 3584 16B-chunks (As 512 + Bs 3072); each wave-issue is
        // entirely As or entirely Bs (boundaries align to 64 chunks).
#pragma unroll
        for (int i = 0; i < 10; ++i) {
            int cb = i * 384 + w * 64;        // wave-uniform chunk base
            if (i == 9 && cb >= 3584 - 64 + 64) { /* only waves 0,1 at i=9 */ }
            if (i == 9 && w >= 2) break;
            int c = (i == 9) ? (3456 + tid) : (cb + lane);
            if (c < 512) {                    // A chunk
                int r  = c >> 3, kss = c & 7;
                int ksg = kss ^ (r & 7);
                load_lds16(A + (size_t)(rowBase + r) * KDIM + kt + ksg * 8,
                           (unsigned short*)SH + c * 8);
            } else {                          // B chunk
                int cc2 = c - 512;
                int n  = cc2 >> 3, kss = cc2 & 7;
                int ksg = kss ^ (n & 7);
                load_lds16(Bt + (size_t)n * KDIM + kt + ksg * 8,
                           (unsigned short*)SH + c * 8);
            }
        }
        __syncthreads();
#pragma unroll
        for (int ks = 0; ks < 2; ++ks) {
            const int sw = (ks * 4 + quad) ^ (cl & 7);   // swizzled chunk slot
            s16x8 a_frag[4], b_frag[4];
#pragma unroll
            for (int i = 0; i < 4; ++i) {
                a_frag[i] = *(const s16x8*)(As + ((i * 16 + cl) * 8 + sw) * 8);
                b_frag[i] = *(const s16x8*)(Bs + ((w * 64 + i * 16 + cl) * 8 + sw) * 8);
            }
#pragma unroll
            for (int i = 0; i < 4; ++i)
#pragma unroll
                for (int j = 0; j < 4; ++j)
                    acc[i][j] = __builtin_amdgcn_mfma_f32_16x16x32_bf16(
                        a_frag[i], b_frag[j], acc[i][j], 0, 0, 0);
        }
        __syncthreads();
    }

    // ---- epilogue: bias + LayerNorm(384) + write ----
    float bv[4], gv[4], btv[4];
#pragma unroll
    for (int j = 0; j < 4; ++j) {
        int col = w * 64 + j * 16 + cl;
        bv[j] = bias[col]; gv[j] = gamma[col]; btv[j] = beta[col];
    }

    // per-row partial sums (each lane: 16 rows x 4 cols), reduce over cl
#pragma unroll
    for (int i = 0; i < 4; ++i) {
#pragma unroll
        for (int r = 0; r < 4; ++r) {
            float s1 = 0.0f, s2 = 0.0f;
#pragma unroll
            for (int j = 0; j < 4; ++j) {
                float v = acc[i][j][r] + bv[j];
                s1 += v; s2 += v * v;
            }
#pragma unroll
            for (int off = 1; off < 16; off <<= 1) {
                s1 += __shfl_xor(s1, off);
                s2 += __shfl_xor(s2, off);
            }
            if (cl == 0) {
                int row = i * 16 + quad * 4 + r;
                atomicAdd(&sred[row], s1);
                atomicAdd(&sred2[row], s2);
            }
        }
    }
    __syncthreads();
    if (tid < 64) {
        float mu  = sred[tid] * (1.0f / (float)DDIM);
        float var = sred2[tid] * (1.0f / (float)DDIM) - mu * mu;
        smean[tid] = mu;
        srstd[tid] = rsqrtf(var + 1e-5f);
    }
    __syncthreads();

#pragma unroll
    for (int i = 0; i < 4; ++i) {
#pragma unroll
        for (int r = 0; r < 4; ++r) {
            int row = i * 16 + quad * 4 + r;
            float mu = smean[row], rs = srstd[row];
            float* crow = C + (size_t)(rowBase + row) * DDIM;
#pragma unroll
            for (int j = 0; j < 4; ++j)
                crow[w * 64 + j * 16 + cl] = (acc[i][j][r] + bv[j] - mu) * rs * gv[j] + btv[j];
        }
    }
}

extern "C" void kernel_launch(void* const* d_in, const int* in_sizes, int n_in,
                              void* d_out, int out_size, void* d_ws, size_t ws_size,
                              hipStream_t stream) {
    const float* img = (const float*)d_in[0];
    const float* pw  = (const float*)d_in[1];
    const float* pb  = (const float*)d_in[2];
    const float* gam = (const float*)d_in[3];
    const float* bet = (const float*)d_in[4];
    float* out = (float*)d_out;

    unsigned short* Abf = (unsigned short*)d_ws;                       // 12544*768*2 = 19267584 B
    unsigned short* Wbf = (unsigned short*)((char*)d_ws + 19267584);   // 384*768*2  = 589824 B
    float* ent = out + (size_t)M_ROWS * DDIM;                          // entropy after x

    hipLaunchKernelGGL(patch_kernel,   dim3(3424), dim3(256), 0, stream,
                       img, pw, Abf, Wbf, ent);
    hipLaunchKernelGGL(gemm_ln_kernel, dim3(196),  dim3(384), 0, stream,
                       Abf, Wbf, pb, gam, bet, out);
}